// Round 3
// baseline (78.010 us; speedup 1.0000x reference)
//
#include <hip/hip_runtime.h>

typedef unsigned short u16;
typedef __attribute__((ext_vector_type(8))) short bf16x8;
typedef __attribute__((ext_vector_type(4))) float f32x4;

#define N_PAT 4096
#define KDIM  1024
#define NMOD  4
#define DDIM  256
#define NT    16              // N_PAT / 256
#define NPAIR 136             // NT*(NT+1)/2
#define KT    32              // KDIM / 32 K-tiles

static __device__ __forceinline__ u16 f2bf(float x) {
  unsigned int u = __builtin_bit_cast(unsigned int, x);
  u += 0x7FFFu + ((u >> 16) & 1u);   // RNE (inputs are finite normals)
  return (u16)(u >> 16);
}

// ---------------------------------------------------------------------------
// prep: per (m,i) row -> norm, missing flag, bf16 normalized+masked embedding
// Y layout: [i][m*256+d]  (K-concatenated modalities), a/b tables fp32.
// Blocks 0..15 additionally precompute eh[q] = exp(h[q]).
// ---------------------------------------------------------------------------
__global__ __launch_bounds__(256) void prep_kernel(
    const float* __restrict__ eb, const float* __restrict__ h,
    u16* __restrict__ Y, float* __restrict__ a_tab, float* __restrict__ b_tab,
    float* __restrict__ eh)
{
  if (blockIdx.x < 16) {
    int q = blockIdx.x * 256 + threadIdx.x;
    eh[q] = expf(h[q]);
  }
  int wid  = threadIdx.x >> 6;
  int lane = threadIdx.x & 63;
  int row  = blockIdx.x * 4 + wid;          // row = m*4096 + i
  int m = row >> 12;
  int i = row & (N_PAT - 1);
  const float* base = eb + (size_t)row * DDIM;
  float4 v = *(const float4*)(base + lane * 4);
  float x0 = base[0];
  int eq = (v.x == x0) & (v.y == x0) & (v.z == x0) & (v.w == x0);
  float ss = v.x * v.x + v.y * v.y + v.z * v.z + v.w * v.w;
#pragma unroll
  for (int o = 32; o; o >>= 1) ss += __shfl_xor(ss, o, 64);
  int missing = __all(eq);
  float nrm   = sqrtf(ss);
  float denom = fmaxf(nrm, 1e-8f);
  float inv   = missing ? 0.0f : (1.0f / denom);
  ushort4 o4;
  o4.x = f2bf(v.x * inv); o4.y = f2bf(v.y * inv);
  o4.z = f2bf(v.z * inv); o4.w = f2bf(v.w * inv);
  *(ushort4*)(Y + (size_t)i * KDIM + m * DDIM + lane * 4) = o4;
  if (lane == 0) {
    float ssim = ss / (denom * denom);       // self-cosine (== ref diagonal)
    a_tab[m * N_PAT + i] = missing ? 0.0f : ssim;
    b_tab[m * N_PAT + i] = missing ? 0.0f : 1.0f;
  }
}

// ---------------------------------------------------------------------------
// cox_sumexp: sumexp[i] = sum_j [t_j >= t_i] * eh[j]. One wave per i.
// ---------------------------------------------------------------------------
__global__ __launch_bounds__(256) void cox_sumexp_kernel(
    const float* __restrict__ t, const float* __restrict__ eh,
    float* __restrict__ sumexp)
{
  int wid = threadIdx.x >> 6, lane = threadIdx.x & 63;
  int i = blockIdx.x * 4 + wid;
  float ti = t[i];
  float s = 0.f;
#pragma unroll
  for (int it = 0; it < 16; ++it) {
    int j = (it * 64 + lane) * 4;
    float4 tv = *(const float4*)(t + j);
    float4 ev = *(const float4*)(eh + j);
    s += (tv.x >= ti) ? ev.x : 0.f;
    s += (tv.y >= ti) ? ev.y : 0.f;
    s += (tv.z >= ti) ? ev.z : 0.f;
    s += (tv.w >= ti) ? ev.w : 0.f;
  }
#pragma unroll
  for (int o = 32; o; o >>= 1) s += __shfl_xor(s, o, 64);
  if (lane == 0) sumexp[i] = s;
}

// ---------------------------------------------------------------------------
// gemm_sim: triangular 256x256 tiles of Yn@Yn^T, ring-4 LDS (BK=32), counted
// vmcnt(4) boundaries (T4), XOR-swizzled LDS (T2, via pre-swizzled source),
// XCD-aware block swizzle (T1), setprio around MFMA (T5).
// 8 waves (2x4); per-wave 128x64 output = 8x4 frags of mfma 16x16x32 bf16.
// ---------------------------------------------------------------------------
__global__ __launch_bounds__(512) void gemm_sim_kernel(
    const u16* __restrict__ Y,
    const float* __restrict__ a_tab, const float* __restrict__ b_tab,
    const float* __restrict__ Mp, float* __restrict__ partials)
{
  __shared__ u16 ring[4][2][256 * 32];      // 128 KB: [slot][A/B][row*32+k]
  __shared__ float tabs[4][NMOD][256];      // 16 KB: aR,bR,aC,bC (epilogue only)
  __shared__ float redbuf[8];

  int praw = blockIdx.x;
  int p = (praw & 7) * 17 + (praw >> 3);    // bijective XCD swizzle (136 = 8*17)
  int by = (int)((sqrtf(8.0f * (float)p + 1.0f) - 1.0f) * 0.5f);
  while ((by + 1) * (by + 2) / 2 <= p) ++by;
  while (by * (by + 1) / 2 > p) --by;
  int bx = p - by * (by + 1) / 2;           // bx <= by
  int brow = bx * 256, bcol = by * 256;

  int tid  = threadIdx.x;
  int lane = tid & 63;
  int wid  = tid >> 6;
  int wr = wid >> 2, wc = wid & 3;

  // Stage one 256x32 matrix (16 KB) of tile tt: LDS dest linear (q*16B),
  // global source chunk-XOR-swizzled so reads can apply the same XOR.
#define STAGE(tt, mat, baserow)                                                \
  {                                                                            \
    int slot_ = (tt) & 3;                                                      \
    _Pragma("unroll")                                                          \
    for (int h_ = 0; h_ < 2; ++h_) {                                           \
      int q_ = tid + h_ * 512;                                                 \
      int r_ = q_ >> 2, c_ = q_ & 3;                                           \
      int cs_ = c_ ^ ((r_ >> 1) & 3);                                          \
      const u16* src_ = Y + (size_t)((baserow) + r_) * KDIM + (tt) * 32 + cs_ * 8; \
      __builtin_amdgcn_global_load_lds(                                        \
          (const __attribute__((address_space(1))) void*)src_,                 \
          (__attribute__((address_space(3))) void*)(&ring[slot_][mat][q_ * 8]),\
          16, 0, 0);                                                           \
    }                                                                          \
  }

  // prologue: stage tiles 0 and 1 (8 loads/thread), wait tile 0 (vmcnt(4))
  STAGE(0, 0, brow); STAGE(0, 1, bcol);
  STAGE(1, 0, brow); STAGE(1, 1, bcol);
  asm volatile("s_waitcnt vmcnt(4)" ::: "memory");
  __builtin_amdgcn_s_barrier();

  const f32x4 zero = {0.f, 0.f, 0.f, 0.f};
  f32x4 acc[8][4];
#pragma unroll
  for (int a = 0; a < 8; ++a)
#pragma unroll
    for (int b = 0; b < 4; ++b) acc[a][b] = zero;

  for (int t = 0; t < KT; ++t) {
    int slot = t & 3;
    const u16* As = &ring[slot][0][0];
    const u16* Bs = &ring[slot][1][0];

    // ---- phase A: stage A(t+2); read B frags + A frags mi0-3; 16 MFMA ----
    if (t + 2 < KT) STAGE(t + 2, 0, brow);
    bf16x8 bfv[4], af0[4];
#pragma unroll
    for (int ni = 0; ni < 4; ++ni) {
      int r = wc * 64 + ni * 16 + (lane & 15);
      int cs = (lane >> 4) ^ ((r >> 1) & 3);
      bfv[ni] = *(const bf16x8*)(Bs + r * 32 + cs * 8);
    }
#pragma unroll
    for (int mi = 0; mi < 4; ++mi) {
      int r = wr * 128 + mi * 16 + (lane & 15);
      int cs = (lane >> 4) ^ ((r >> 1) & 3);
      af0[mi] = *(const bf16x8*)(As + r * 32 + cs * 8);
    }
    __builtin_amdgcn_s_setprio(1);
#pragma unroll
    for (int mi = 0; mi < 4; ++mi)
#pragma unroll
      for (int ni = 0; ni < 4; ++ni)
        acc[mi][ni] = __builtin_amdgcn_mfma_f32_16x16x32_bf16(
            af0[mi], bfv[ni], acc[mi][ni], 0, 0, 0);
    __builtin_amdgcn_s_setprio(0);
    __builtin_amdgcn_s_barrier();

    // ---- phase B: stage B(t+2); read A frags mi4-7; 16 MFMA ----
    if (t + 2 < KT) STAGE(t + 2, 1, bcol);
    bf16x8 af1[4];
#pragma unroll
    for (int mi = 0; mi < 4; ++mi) {
      int r = wr * 128 + (mi + 4) * 16 + (lane & 15);
      int cs = (lane >> 4) ^ ((r >> 1) & 3);
      af1[mi] = *(const bf16x8*)(As + r * 32 + cs * 8);
    }
    __builtin_amdgcn_s_setprio(1);
#pragma unroll
    for (int mi = 0; mi < 4; ++mi)
#pragma unroll
      for (int ni = 0; ni < 4; ++ni)
        acc[mi + 4][ni] = __builtin_amdgcn_mfma_f32_16x16x32_bf16(
            af1[mi], bfv[ni], acc[mi + 4][ni], 0, 0, 0);
    __builtin_amdgcn_s_setprio(0);
    // counted boundary wait: tile t+1's loads (issued during t-1) are done
    // when <=4 remain (the 4 issued this iteration for t+2). Tail: drain.
    if (t < KT - 2) { asm volatile("s_waitcnt vmcnt(4)" ::: "memory"); }
    else            { asm volatile("s_waitcnt vmcnt(0)" ::: "memory"); }
    __builtin_amdgcn_s_barrier();
  }
#undef STAGE

  // ---- epilogue: load a/b tables to LDS, fused relu-reduction ----
  for (int q = tid; q < 4 * NMOD * 256; q += 512) {
    int tb = q >> 10;                       // 0=aR 1=bR 2=aC 3=bC
    int m  = (q >> 8) & 3;
    int i  = q & 255;
    int base = (tb & 2) ? bcol : brow;
    const float* srct = (tb & 1) ? b_tab : a_tab;
    tabs[tb][m][i] = srct[m * N_PAT + base + i];
  }
  __syncthreads();

  float Mv = Mp[0];
  float lsum = 0.0f;
  bool offd = (bx != by);
#pragma unroll
  for (int mi = 0; mi < 8; ++mi) {
#pragma unroll
    for (int j = 0; j < 4; ++j) {
      int il = wr * 128 + mi * 16 + ((lane >> 4) << 2) + j;  // C row (local)
      float ar[NMOD], br[NMOD];
#pragma unroll
      for (int m = 0; m < NMOD; ++m) {
        ar[m] = tabs[0][m][il];
        br[m] = tabs[1][m][il];
      }
#pragma unroll
      for (int ni = 0; ni < 4; ++ni) {
        int jl = wc * 64 + ni * 16 + (lane & 15);            // C col (local)
        float msim = acc[mi][ni][j];
        float p1 = 0.f;
#pragma unroll
        for (int m = 0; m < NMOD; ++m) p1 += ar[m] * tabs[3][m][jl];
        float t1 = Mv - msim + p1;
        if ((brow + il) != (bcol + jl) && t1 > 0.f) lsum += t1;
        if (offd) {
          float p2 = 0.f;
#pragma unroll
          for (int m = 0; m < NMOD; ++m) p2 += tabs[2][m][jl] * br[m];
          float t2 = Mv - msim + p2;
          if (t2 > 0.f) lsum += t2;
        }
      }
    }
  }
#pragma unroll
  for (int o = 32; o; o >>= 1) lsum += __shfl_xor(lsum, o, 64);
  if (lane == 0) redbuf[wid] = lsum;
  __syncthreads();
  if (tid == 0) {
    float s = 0.f;
#pragma unroll
    for (int w = 0; w < 8; ++w) s += redbuf[w];
    partials[p] = s;
  }
}

// ---------------------------------------------------------------------------
// finalize: cox = -sum(ev*(h - log(sumexp)))/sum(ev); out = cox + sum(partials)
// ---------------------------------------------------------------------------
__global__ __launch_bounds__(256) void finalize_kernel(
    const float* __restrict__ h, const int* __restrict__ ev,
    const float* __restrict__ sumexp, const float* __restrict__ partials,
    float* __restrict__ out)
{
  __shared__ float rb[12];
  int tid = threadIdx.x, lane = tid & 63, wid = tid >> 6;
  float num = 0.f, den = 0.f, sim = 0.f;
  for (int i = tid; i < N_PAT; i += 256) {
    float e = (float)ev[i];
    num += e * (h[i] - logf(sumexp[i]));
    den += e;
  }
  for (int q = tid; q < NPAIR; q += 256) sim += partials[q];
#pragma unroll
  for (int o = 32; o; o >>= 1) {
    num += __shfl_xor(num, o, 64);
    den += __shfl_xor(den, o, 64);
    sim += __shfl_xor(sim, o, 64);
  }
  if (lane == 0) { rb[wid] = num; rb[4 + wid] = den; rb[8 + wid] = sim; }
  __syncthreads();
  if (tid == 0) {
    float n = rb[0] + rb[1] + rb[2] + rb[3];
    float d = rb[4] + rb[5] + rb[6] + rb[7];
    float s = rb[8] + rb[9] + rb[10] + rb[11];
    out[0] = -n / d + s;
  }
}

// ---------------------------------------------------------------------------
extern "C" void kernel_launch(void* const* d_in, const int* in_sizes, int n_in,
                              void* d_out, int out_size, void* d_ws, size_t ws_size,
                              hipStream_t stream)
{
  const float* h  = (const float*)d_in[0];
  const float* eb = (const float*)d_in[1];
  const float* tm = (const float*)d_in[2];
  const int*   ev = (const int*)d_in[3];
  const float* Mp = (const float*)d_in[4];
  float* out = (float*)d_out;

  char* ws = (char*)d_ws;
  u16*   Y        = (u16*)ws;                                   // 8 MB
  float* a_tab    = (float*)(ws + (size_t)8 * 1024 * 1024);     // 64 KB
  float* b_tab    = a_tab + NMOD * N_PAT;                       // 64 KB
  float* sumexp   = b_tab + NMOD * N_PAT;                       // 16 KB
  float* partials = sumexp + N_PAT;                             // 136 floats
  float* eh       = partials + 1024;                            // 16 KB

  prep_kernel<<<dim3(N_PAT * NMOD / 4), dim3(256), 0, stream>>>(eb, h, Y, a_tab, b_tab, eh);
  cox_sumexp_kernel<<<dim3(N_PAT / 4), dim3(256), 0, stream>>>(tm, eh, sumexp);
  gemm_sim_kernel<<<dim3(NPAIR), dim3(512), 0, stream>>>(Y, a_tab, b_tab, Mp, partials);
  finalize_kernel<<<dim3(1), dim3(256), 0, stream>>>(h, ev, sumexp, partials, out);
}

// Round 4
// 56.428 us; speedup vs baseline: 1.3825x; 1.3825x over previous
//
#include <hip/hip_runtime.h>

typedef unsigned short u16;
typedef signed char s8;
typedef __attribute__((ext_vector_type(4))) int i32x4;

#define N_PAT 4096
#define KROW  1024            // i8 elements per Y row
#define NMOD  4
#define DDIM  256
#define NTILE 32              // N_PAT / 128
#define NPAIR 528             // NTILE*(NTILE+1)/2
#define KT    8               // K-iterations (BK=128)
#define INV127SQ 6.2000124e-5f  // 1/127^2

// ---------------------------------------------------------------------------
// prep: per (m,i) row -> norm, missing flag, int8 normalized+masked embedding
// Yq layout: [i][m*256+d] int8 (K-concatenated modalities); a/b tables fp32.
// Blocks 0..15 additionally precompute eh[q] = exp(h[q]).
// ---------------------------------------------------------------------------
__global__ __launch_bounds__(256) void prep_kernel(
    const float* __restrict__ eb, const float* __restrict__ h,
    s8* __restrict__ Yq, float* __restrict__ a_tab, float* __restrict__ b_tab,
    float* __restrict__ eh)
{
  if (blockIdx.x < 16) {
    int q = blockIdx.x * 256 + threadIdx.x;
    eh[q] = expf(h[q]);
  }
  int wid  = threadIdx.x >> 6;
  int lane = threadIdx.x & 63;
  int row  = blockIdx.x * 4 + wid;          // row = m*4096 + i
  int m = row >> 12;
  int i = row & (N_PAT - 1);
  const float* base = eb + (size_t)row * DDIM;
  float4 v = *(const float4*)(base + lane * 4);
  float x0 = base[0];
  int eq = (v.x == x0) & (v.y == x0) & (v.z == x0) & (v.w == x0);
  float ss = v.x * v.x + v.y * v.y + v.z * v.z + v.w * v.w;
#pragma unroll
  for (int o = 32; o; o >>= 1) ss += __shfl_xor(ss, o, 64);
  int missing = __all(eq);
  float nrm   = sqrtf(ss);
  float denom = fmaxf(nrm, 1e-8f);
  float inv   = missing ? 0.0f : (127.0f / denom);
  int q0 = __float2int_rn(v.x * inv);
  int q1 = __float2int_rn(v.y * inv);
  int q2 = __float2int_rn(v.z * inv);
  int q3 = __float2int_rn(v.w * inv);
  unsigned int packed = (q0 & 0xFF) | ((q1 & 0xFF) << 8) |
                        ((q2 & 0xFF) << 16) | ((q3 & 0xFF) << 24);
  *(unsigned int*)(Yq + (size_t)i * KROW + m * DDIM + lane * 4) = packed;
  if (lane == 0) {
    float ssim = ss / (denom * denom);       // self-cosine (== ref diagonal)
    a_tab[m * N_PAT + i] = missing ? 0.0f : ssim;
    b_tab[m * N_PAT + i] = missing ? 0.0f : 1.0f;
  }
}

// ---------------------------------------------------------------------------
// cox_sumexp: sumexp[i] = sum_j [t_j >= t_i] * eh[j]. One wave per i.
// ---------------------------------------------------------------------------
__global__ __launch_bounds__(256) void cox_sumexp_kernel(
    const float* __restrict__ t, const float* __restrict__ eh,
    float* __restrict__ sumexp)
{
  int wid = threadIdx.x >> 6, lane = threadIdx.x & 63;
  int i = blockIdx.x * 4 + wid;
  float ti = t[i];
  float s = 0.f;
#pragma unroll
  for (int it = 0; it < 16; ++it) {
    int j = (it * 64 + lane) * 4;
    float4 tv = *(const float4*)(t + j);
    float4 ev = *(const float4*)(eh + j);
    s += (tv.x >= ti) ? ev.x : 0.f;
    s += (tv.y >= ti) ? ev.y : 0.f;
    s += (tv.z >= ti) ? ev.z : 0.f;
    s += (tv.w >= ti) ? ev.w : 0.f;
  }
#pragma unroll
  for (int o = 32; o; o >>= 1) s += __shfl_xor(s, o, 64);
  if (lane == 0) sumexp[i] = s;
}

// ---------------------------------------------------------------------------
// gemm_sim: triangular 128x128 tiles of Yq@Yq^T (int8), BK=128, double-buffer,
// stage-issue-early + vmcnt(0)+barrier per iter, XOR chunk swizzle (2-way =
// free), XCD swizzle, setprio. 4 waves (2x2); per-wave 64x64 = 4x4 frags of
// mfma_i32_16x16x64_i8. Fused relu-reduction epilogue.
// ---------------------------------------------------------------------------
__global__ __launch_bounds__(256) void gemm_sim_kernel(
    const s8* __restrict__ Yq,
    const float* __restrict__ a_tab, const float* __restrict__ b_tab,
    const float* __restrict__ Mp, float* __restrict__ partials)
{
  __shared__ s8 Abuf[2][128 * 128];         // 2 x 16 KB
  __shared__ s8 Bbuf[2][128 * 128];         // 2 x 16 KB
  __shared__ float tabs[4][NMOD][128];      // 8 KB: aR,bR,aC,bC
  __shared__ float redbuf[4];

  int praw = blockIdx.x;
  int p = (praw & 7) * 66 + (praw >> 3);    // bijective XCD swizzle (528 = 8*66)
  int by = (int)((sqrtf(8.0f * (float)p + 1.0f) - 1.0f) * 0.5f);
  while ((by + 1) * (by + 2) / 2 <= p) ++by;
  while (by * (by + 1) / 2 > p) --by;
  int bx = p - by * (by + 1) / 2;           // bx <= by
  int brow = bx * 128, bcol = by * 128;

  int tid  = threadIdx.x;
  int lane = tid & 63;
  int wid  = tid >> 6;
  int wr = wid >> 1, wc = wid & 1;

  // Stage A/B tiles (128 rows x 128 i8 each) for K-iter tt into buffer pb.
  // LDS dest linear in q (lane-contiguous, rule #21); global source chunk
  // XOR-swizzled (cs = c ^ (r&7)); reads apply the same XOR.
#define STAGE(tt, pb)                                                          \
  {                                                                            \
    _Pragma("unroll")                                                          \
    for (int h_ = 0; h_ < 4; ++h_) {                                           \
      int q_ = tid + h_ * 256;              /* 1024 chunks of 16B */           \
      int r_ = q_ >> 3, c_ = q_ & 7;                                           \
      int cs_ = c_ ^ (r_ & 7);                                                 \
      const s8* sA_ = Yq + (size_t)(brow + r_) * KROW + (tt) * 128 + cs_ * 16; \
      const s8* sB_ = Yq + (size_t)(bcol + r_) * KROW + (tt) * 128 + cs_ * 16; \
      __builtin_amdgcn_global_load_lds(                                        \
          (const __attribute__((address_space(1))) void*)sA_,                  \
          (__attribute__((address_space(3))) void*)(&Abuf[pb][q_ * 16]),       \
          16, 0, 0);                                                           \
      __builtin_amdgcn_global_load_lds(                                        \
          (const __attribute__((address_space(1))) void*)sB_,                  \
          (__attribute__((address_space(3))) void*)(&Bbuf[pb][q_ * 16]),       \
          16, 0, 0);                                                           \
    }                                                                          \
  }

  STAGE(0, 0);
  asm volatile("s_waitcnt vmcnt(0)" ::: "memory");
  __builtin_amdgcn_s_barrier();

  const i32x4 zero = {0, 0, 0, 0};
  i32x4 acc[4][4];
#pragma unroll
  for (int a = 0; a < 4; ++a)
#pragma unroll
    for (int b = 0; b < 4; ++b) acc[a][b] = zero;

  for (int t = 0; t < KT; ++t) {
    int pb = t & 1;
    if (t + 1 < KT) STAGE(t + 1, pb ^ 1);   // issue next-tile loads FIRST

    // ds_read fragments (16B/lane each, 2-way-free after XOR swizzle)
    i32x4 af[4][2], bf[4][2];
#pragma unroll
    for (int mi = 0; mi < 4; ++mi) {
      int r = wr * 64 + mi * 16 + (lane & 15);
#pragma unroll
      for (int kk = 0; kk < 2; ++kk) {
        int c = (kk * 4 + (lane >> 4)) ^ (r & 7);
        af[mi][kk] = *(const i32x4*)(&Abuf[pb][r * 128 + c * 16]);
      }
    }
#pragma unroll
    for (int ni = 0; ni < 4; ++ni) {
      int r = wc * 64 + ni * 16 + (lane & 15);
#pragma unroll
      for (int kk = 0; kk < 2; ++kk) {
        int c = (kk * 4 + (lane >> 4)) ^ (r & 7);
        bf[ni][kk] = *(const i32x4*)(&Bbuf[pb][r * 128 + c * 16]);
      }
    }
    __builtin_amdgcn_s_setprio(1);
#pragma unroll
    for (int kk = 0; kk < 2; ++kk)
#pragma unroll
      for (int mi = 0; mi < 4; ++mi)
#pragma unroll
        for (int ni = 0; ni < 4; ++ni)
          acc[mi][ni] = __builtin_amdgcn_mfma_i32_16x16x64_i8(
              af[mi][kk], bf[ni][kk], acc[mi][ni], 0, 0, 0);
    __builtin_amdgcn_s_setprio(0);
    asm volatile("s_waitcnt vmcnt(0)" ::: "memory");  // next tile landed
    __builtin_amdgcn_s_barrier();
  }
#undef STAGE

  // ---- epilogue: load a/b tables to LDS, fused relu-reduction ----
  for (int q = tid; q < 4 * NMOD * 128; q += 256) {
    int tb = q >> 9;                        // 0=aR 1=bR 2=aC 3=bC
    int m  = (q >> 7) & 3;
    int i  = q & 127;
    int base = (tb & 2) ? bcol : brow;
    const float* srct = (tb & 1) ? b_tab : a_tab;
    tabs[tb][m][i] = srct[m * N_PAT + base + i];
  }
  __syncthreads();

  float Mv = Mp[0];
  float lsum = 0.0f;
  bool offd = (bx != by);
#pragma unroll
  for (int mi = 0; mi < 4; ++mi) {
#pragma unroll
    for (int ni = 0; ni < 4; ++ni) {
#pragma unroll
      for (int j = 0; j < 4; ++j) {
        int il = wr * 64 + mi * 16 + ((lane >> 4) << 2) + j;  // C row (local)
        int jl = wc * 64 + ni * 16 + (lane & 15);             // C col (local)
        float msim = (float)acc[mi][ni][j] * INV127SQ;
        float p1 = 0.f;
#pragma unroll
        for (int m = 0; m < NMOD; ++m) p1 += tabs[0][m][il] * tabs[3][m][jl];
        float t1 = Mv - msim + p1;
        if ((brow + il) != (bcol + jl) && t1 > 0.f) lsum += t1;
        if (offd) {
          float p2 = 0.f;
#pragma unroll
          for (int m = 0; m < NMOD; ++m) p2 += tabs[2][m][jl] * tabs[1][m][il];
          float t2 = Mv - msim + p2;
          if (t2 > 0.f) lsum += t2;
        }
      }
    }
  }
#pragma unroll
  for (int o = 32; o; o >>= 1) lsum += __shfl_xor(lsum, o, 64);
  if (lane == 0) redbuf[wid] = lsum;
  __syncthreads();
  if (tid == 0) partials[p] = redbuf[0] + redbuf[1] + redbuf[2] + redbuf[3];
}

// ---------------------------------------------------------------------------
// finalize: cox = -sum(ev*(h - log(sumexp)))/sum(ev); out = cox + sum(partials)
// ---------------------------------------------------------------------------
__global__ __launch_bounds__(256) void finalize_kernel(
    const float* __restrict__ h, const int* __restrict__ ev,
    const float* __restrict__ sumexp, const float* __restrict__ partials,
    float* __restrict__ out)
{
  __shared__ float rb[12];
  int tid = threadIdx.x, lane = tid & 63, wid = tid >> 6;
  float num = 0.f, den = 0.f, sim = 0.f;
  for (int i = tid; i < N_PAT; i += 256) {
    float e = (float)ev[i];
    num += e * (h[i] - logf(sumexp[i]));
    den += e;
  }
  for (int q = tid; q < NPAIR; q += 256) sim += partials[q];
#pragma unroll
  for (int o = 32; o; o >>= 1) {
    num += __shfl_xor(num, o, 64);
    den += __shfl_xor(den, o, 64);
    sim += __shfl_xor(sim, o, 64);
  }
  if (lane == 0) { rb[wid] = num; rb[4 + wid] = den; rb[8 + wid] = sim; }
  __syncthreads();
  if (tid == 0) {
    float n = rb[0] + rb[1] + rb[2] + rb[3];
    float d = rb[4] + rb[5] + rb[6] + rb[7];
    float s = rb[8] + rb[9] + rb[10] + rb[11];
    out[0] = -n / d + s;
  }
}

// ---------------------------------------------------------------------------
extern "C" void kernel_launch(void* const* d_in, const int* in_sizes, int n_in,
                              void* d_out, int out_size, void* d_ws, size_t ws_size,
                              hipStream_t stream)
{
  const float* h  = (const float*)d_in[0];
  const float* eb = (const float*)d_in[1];
  const float* tm = (const float*)d_in[2];
  const int*   ev = (const int*)d_in[3];
  const float* Mp = (const float*)d_in[4];
  float* out = (float*)d_out;

  char* ws = (char*)d_ws;
  s8*    Yq       = (s8*)ws;                                    // 4 MB
  float* a_tab    = (float*)(ws + (size_t)4 * 1024 * 1024);     // 64 KB
  float* b_tab    = a_tab + NMOD * N_PAT;                       // 64 KB
  float* sumexp   = b_tab + NMOD * N_PAT;                       // 16 KB
  float* partials = sumexp + N_PAT;                             // 528 floats
  float* eh       = partials + 1024;                            // 16 KB

  prep_kernel<<<dim3(N_PAT * NMOD / 4), dim3(256), 0, stream>>>(eb, h, Yq, a_tab, b_tab, eh);
  cox_sumexp_kernel<<<dim3(N_PAT / 4), dim3(256), 0, stream>>>(tm, eh, sumexp);
  gemm_sim_kernel<<<dim3(NPAIR), dim3(256), 0, stream>>>(Yq, a_tab, b_tab, Mp, partials);
  finalize_kernel<<<dim3(1), dim3(256), 0, stream>>>(h, ev, sumexp, partials, out);
}